// Round 9
// baseline (138.728 us; speedup 1.0000x reference)
//
#include <hip/hip_runtime.h>
#include <hip/hip_bf16.h>

#define D_DIM 768
#define K_CL  512
#define BM    64
#define BK    32
#define NSTEP 24          // 768 / 32
#define CSTRIDE (K_CL * D_DIM)   // ushorts per B copy (393216 = 768 KB)

using f32x4 = __attribute__((ext_vector_type(4))) float;
using s16x8 = __attribute__((ext_vector_type(8))) short;
using u16x8 = __attribute__((ext_vector_type(8))) unsigned short;
using u16x4 = __attribute__((ext_vector_type(4))) unsigned short;
typedef unsigned int u32;

static __device__ __forceinline__ unsigned short f2bf(float f) {
    __hip_bfloat16 h = __float2bfloat16(f);   // RTN
    unsigned short u;
    __builtin_memcpy(&u, &h, 2);
    return u;
}

static __device__ __forceinline__ void gload_lds16(const void* g, void* l) {
    __builtin_amdgcn_global_load_lds(
        (const __attribute__((address_space(1))) u32*)g,
        (__attribute__((address_space(3))) u32*)l, 16, 0, 0);
}

// Prepass: C[512][768] fp32 -> bf16, replicated ncop times (one copy per
// XCD so main-kernel B reads are XCD-local L2 hits).  "LDS image" layout
// per copy: granule (16B) g = t*2048 + r*4 + (s ^ ((r>>1)&3)), holding
// C[r][t*32 + s*8 .. +8).  Also c_sq[512].
__global__ void prep_centers_kernel(const float* __restrict__ C,
                                    unsigned short* __restrict__ Cbws,
                                    float* __restrict__ csq, int ncop) {
    const int r = blockIdx.x;          // 0..511
    const int l = threadIdx.x;         // 0..63
    const float* src = C + (size_t)r * D_DIM;
    float sq = 0.f;
#pragma unroll
    for (int jj = 0; jj < 2; ++jj) {
        const int j = l + jj * 64;     // 0..127, only 0..95 valid
        if (j < 96) {
            const int t = j >> 2, s = j & 3;
            const int k0 = t * 32 + s * 8;
            f32x4 v0 = *reinterpret_cast<const f32x4*>(src + k0);
            f32x4 v1 = *reinterpret_cast<const f32x4*>(src + k0 + 4);
            u16x8 b;
            b[0] = f2bf(v0[0]); b[1] = f2bf(v0[1]); b[2] = f2bf(v0[2]); b[3] = f2bf(v0[3]);
            b[4] = f2bf(v1[0]); b[5] = f2bf(v1[1]); b[6] = f2bf(v1[2]); b[7] = f2bf(v1[3]);
            sq += v0[0]*v0[0] + v0[1]*v0[1] + v0[2]*v0[2] + v0[3]*v0[3]
                + v1[0]*v1[0] + v1[1]*v1[1] + v1[2]*v1[2] + v1[3]*v1[3];
            const int g = t * 2048 + r * 4 + (s ^ ((r >> 1) & 3));
            for (int c = 0; c < ncop; ++c)
                *reinterpret_cast<u16x8*>(Cbws + (size_t)c * CSTRIDE + (size_t)g * 8) = b;
        }
    }
#pragma unroll
    for (int m = 1; m < 64; m <<= 1) sq += __shfl_xor(sq, m, 64);
    if (l == 0) csq[r] = sq;
}

// Main: 64 rows x 512 clusters per block, 8 waves, wave tile 64x64.
// B via global_load_lds dbuf from the XCD-LOCAL replica (blockIdx & cmask),
// counted vmcnt across raw barriers.  A reg->LDS dbuf, verified swizzles.
__global__ __launch_bounds__(512, 4) void dec_main_kernel(
    const float* __restrict__ X,
    const unsigned short* __restrict__ Cbws,
    const float* __restrict__ csq,
    const float* __restrict__ alpha_ptr,
    float* __restrict__ out, int cmask)
{
    __shared__ unsigned short Al[2][BM * BK];      // 2 * 4 KB
    __shared__ unsigned short Bl[2][K_CL * BK];    // 2 * 32 KB
    __shared__ float part[8][BM];                  // 2 KB
    __shared__ float xsql[BM];
    __shared__ float invl[BM];

    const int tid  = threadIdx.x;      // 0..511
    const int lane = tid & 63;
    const int wn   = tid >> 6;         // 0..7
    const int m0   = blockIdx.x * BM;

    // XCD-local B replica (round-robin dispatch: blockIdx % 8 tracks XCD)
    const unsigned short* Cb = Cbws + (size_t)(blockIdx.x & cmask) * CSTRIDE;

    // A staging: 8 threads per row, float4 each
    const int arow  = tid >> 3;
    const int acol8 = tid & 7;
    const float* aptr = X + (size_t)(m0 + arow) * D_DIM + acol8 * 4;
    const int awbyte = arow * 64
                     + ((((acol8 >> 1) ^ ((arow >> 1) & 3))) << 4)
                     + (acol8 & 1) * 8;

    // fragment read offsets (XOR-swizzled, verified 0-conflict)
    const int fr = lane & 15;
    const int fg = lane >> 4;
    int aoff[4], boff[4];
#pragma unroll
    for (int mf = 0; mf < 4; ++mf) {
        const int r = mf * 16 + fr;
        aoff[mf] = r * 64 + ((fg ^ ((r >> 1) & 3)) << 4);
    }
#pragma unroll
    for (int nf = 0; nf < 4; ++nf) {
        const int r = wn * 64 + nf * 16 + fr;
        boff[nf] = r * 64 + ((fg ^ ((r >> 1) & 3)) << 4);
    }

    f32x4 acc[4][4] = {};
    float sqp = 0.f;

    // ---- prologue ----
    f32x4 areg = *reinterpret_cast<const f32x4*>(aptr);         // A tile 0
    {
        const unsigned short* bs = Cb + (size_t)tid * 8;
#pragma unroll
        for (int q = 0; q < 4; ++q)
            gload_lds16(bs + (size_t)q * 512 * 8,
                        (char*)&Bl[0][0] + ((size_t)q * 512 + tid) * 16);
    }
    {   // stage A(0)
        u16x4 ab;
        ab[0] = f2bf(areg[0]); ab[1] = f2bf(areg[1]);
        ab[2] = f2bf(areg[2]); ab[3] = f2bf(areg[3]);
        sqp += areg[0]*areg[0] + areg[1]*areg[1] + areg[2]*areg[2] + areg[3]*areg[3];
        *reinterpret_cast<u16x4*>((char*)&Al[0][0] + awbyte) = ab;
    }
    areg = *reinterpret_cast<const f32x4*>(aptr + BK);          // A tile 1
    asm volatile("s_waitcnt vmcnt(1) lgkmcnt(0)" ::: "memory"); // B(0) done
    __builtin_amdgcn_sched_barrier(0);
    __builtin_amdgcn_s_barrier();

#pragma unroll
    for (int t = 0; t < NSTEP; ++t) {
        const int buf = t & 1;
        // 1. issue B-DMA(t+1) -> buf^1
        if (t + 1 < NSTEP) {
            const unsigned short* bs = Cb + (size_t)(t + 1) * 2048 * 8 + (size_t)tid * 8;
#pragma unroll
            for (int q = 0; q < 4; ++q)
                gload_lds16(bs + (size_t)q * 512 * 8,
                            (char*)&Bl[buf ^ 1][0] + ((size_t)q * 512 + tid) * 16);
        }
        // 2. compute(t)
        {
            s16x8 afr[4];
#pragma unroll
            for (int mf = 0; mf < 4; ++mf)
                afr[mf] = *reinterpret_cast<const s16x8*>((const char*)&Al[buf][0] + aoff[mf]);
            __builtin_amdgcn_s_setprio(1);
#pragma unroll
            for (int nf = 0; nf < 4; ++nf) {
                s16x8 bfr = *reinterpret_cast<const s16x8*>((const char*)&Bl[buf][0] + boff[nf]);
#pragma unroll
                for (int mf = 0; mf < 4; ++mf)
                    acc[mf][nf] = __builtin_amdgcn_mfma_f32_16x16x32_bf16(
                        afr[mf], bfr, acc[mf][nf], 0, 0, 0);
            }
            __builtin_amdgcn_s_setprio(0);
        }
        // 3. stage A(t+1), prefetch A(t+2), counted wait + barrier
        if (t + 1 < NSTEP) {
            u16x4 ab;
            ab[0] = f2bf(areg[0]); ab[1] = f2bf(areg[1]);
            ab[2] = f2bf(areg[2]); ab[3] = f2bf(areg[3]);
            sqp += areg[0]*areg[0] + areg[1]*areg[1] + areg[2]*areg[2] + areg[3]*areg[3];
            *reinterpret_cast<u16x4*>((char*)&Al[buf ^ 1][0] + awbyte) = ab;
            if (t + 2 < NSTEP) {
                areg = *reinterpret_cast<const f32x4*>(aptr + (t + 2) * BK);
                asm volatile("s_waitcnt vmcnt(1) lgkmcnt(0)" ::: "memory"); // B(t+1) done
            } else {
                asm volatile("s_waitcnt vmcnt(0) lgkmcnt(0)" ::: "memory");
            }
            __builtin_amdgcn_sched_barrier(0);
            __builtin_amdgcn_s_barrier();
        }
    }

    // ---- ||x||^2 per row ----
    sqp += __shfl_xor(sqp, 1, 64);
    sqp += __shfl_xor(sqp, 2, 64);
    sqp += __shfl_xor(sqp, 4, 64);
    if ((tid & 7) == 0) xsql[arow] = sqp;
    __syncthreads();

    const float alpha     = alpha_ptr[0];
    const float inv_alpha = 1.0f / alpha;
    const float power     = 0.5f * (alpha + 1.0f);
    const bool  p1        = (power == 1.0f);

    float csqr[4];
#pragma unroll
    for (int nf = 0; nf < 4; ++nf)
        csqr[nf] = csq[wn * 64 + nf * 16 + fr];

    if (p1) {
#pragma unroll
        for (int mf = 0; mf < 4; ++mf) {
#pragma unroll
            for (int j = 0; j < 4; ++j) {
                const int rloc = mf * 16 + fg * 4 + j;
                const float xs = xsql[rloc];
                float rp = 0.f;
#pragma unroll
                for (int nf = 0; nf < 4; ++nf) {
                    float d2 = xs + csqr[nf] - 2.0f * acc[mf][nf][j];
                    d2 = fmaxf(d2, 0.0f);
                    const float nm = 1.0f / (1.0f + d2 * inv_alpha);
                    acc[mf][nf][j] = nm;
                    rp += nm;
                }
#pragma unroll
                for (int m = 1; m < 16; m <<= 1) rp += __shfl_xor(rp, m, 64);
                if (fr == 0) part[wn][rloc] = rp;
            }
        }
    } else {
#pragma unroll
        for (int mf = 0; mf < 4; ++mf) {
#pragma unroll
            for (int j = 0; j < 4; ++j) {
                const int rloc = mf * 16 + fg * 4 + j;
                const float xs = xsql[rloc];
                float rp = 0.f;
#pragma unroll
                for (int nf = 0; nf < 4; ++nf) {
                    float d2 = xs + csqr[nf] - 2.0f * acc[mf][nf][j];
                    d2 = fmaxf(d2, 0.0f);
                    const float base = 1.0f + d2 * inv_alpha;
                    const float nm = exp2f(-power * log2f(base));
                    acc[mf][nf][j] = nm;
                    rp += nm;
                }
#pragma unroll
                for (int m = 1; m < 16; m <<= 1) rp += __shfl_xor(rp, m, 64);
                if (fr == 0) part[wn][rloc] = rp;
            }
        }
    }
    __syncthreads();
    if (tid < BM) {
        float s = 0.f;
#pragma unroll
        for (int w = 0; w < 8; ++w) s += part[w][tid];
        invl[tid] = 1.0f / s;
    }
    __syncthreads();

#pragma unroll
    for (int mf = 0; mf < 4; ++mf) {
#pragma unroll
        for (int j = 0; j < 4; ++j) {
            const int rloc = mf * 16 + fg * 4 + j;
            const float iv = invl[rloc];
            float* orow = out + (size_t)(m0 + rloc) * K_CL + wn * 64 + fr;
#pragma unroll
            for (int nf = 0; nf < 4; ++nf)
                orow[nf * 16] = acc[mf][nf][j] * iv;
        }
    }
}

extern "C" void kernel_launch(void* const* d_in, const int* in_sizes, int n_in,
                              void* d_out, int out_size, void* d_ws, size_t ws_size,
                              hipStream_t stream) {
    const float* X     = (const float*)d_in[0];
    const float* C     = (const float*)d_in[1];
    const float* alpha = (const float*)d_in[2];
    float* out = (float*)d_out;
    const int N = in_sizes[0] / D_DIM;   // 65536

    // ws layout: csq[512] f32 (2 KB), then ncop B replicas of 768 KB
    float* csq = (float*)d_ws;
    unsigned short* Cbws = (unsigned short*)((char*)d_ws + 2048);

    int ncop = 8;
    while (ncop > 1 && 2048 + (size_t)ncop * CSTRIDE * sizeof(unsigned short) > ws_size)
        ncop >>= 1;

    prep_centers_kernel<<<K_CL, 64, 0, stream>>>(C, Cbws, csq, ncop);
    dec_main_kernel<<<N / BM, 512, 0, stream>>>(X, Cbws, csq, alpha, out, ncop - 1);
}

// Round 11
// 137.478 us; speedup vs baseline: 1.0091x; 1.0091x over previous
//
#include <hip/hip_runtime.h>
#include <hip/hip_bf16.h>

#define D_DIM 768
#define K_CL  512
#define BM    64
#define BK    32
#define NSTEP 24          // 768 / 32

using f32x4 = __attribute__((ext_vector_type(4))) float;
using s16x8 = __attribute__((ext_vector_type(8))) short;
using u16x8 = __attribute__((ext_vector_type(8))) unsigned short;
using u16x4 = __attribute__((ext_vector_type(4))) unsigned short;
typedef unsigned int u32;

static __device__ __forceinline__ unsigned short f2bf(float f) {
    __hip_bfloat16 h = __float2bfloat16(f);   // RTN
    unsigned short u;
    __builtin_memcpy(&u, &h, 2);
    return u;
}

static __device__ __forceinline__ void gload_lds16(const void* g, void* l) {
    __builtin_amdgcn_global_load_lds(
        (const __attribute__((address_space(1))) u32*)g,
        (__attribute__((address_space(3))) u32*)l, 16, 0, 0);
}

// Prepass (R2-verified): C[512][768] fp32 -> bf16 ws in "LDS image" layout:
// granule (16B = 8 bf16) g = t*2048 + r*4 + (s ^ ((r>>1)&3)) holds
// C[r][t*32 + s*8 .. +8).  Rows r in [wn*64, wn*64+64) occupy the contiguous
// granule range t*2048 + wn*256 + [0,256) -> per-wave slices DMA linearly.
__global__ void prep_centers_kernel(const float* __restrict__ C,
                                    unsigned short* __restrict__ Cbws,
                                    float* __restrict__ csq) {
    const int r = blockIdx.x;          // 0..511
    const int l = threadIdx.x;         // 0..63
    const float* src = C + (size_t)r * D_DIM;
    float sq = 0.f;
#pragma unroll
    for (int jj = 0; jj < 2; ++jj) {
        const int j = l + jj * 64;     // 0..127, only 0..95 valid
        if (j < 96) {
            const int t = j >> 2, s = j & 3;
            const int k0 = t * 32 + s * 8;
            f32x4 v0 = *reinterpret_cast<const f32x4*>(src + k0);
            f32x4 v1 = *reinterpret_cast<const f32x4*>(src + k0 + 4);
            u16x8 b;
            b[0] = f2bf(v0[0]); b[1] = f2bf(v0[1]); b[2] = f2bf(v0[2]); b[3] = f2bf(v0[3]);
            b[4] = f2bf(v1[0]); b[5] = f2bf(v1[1]); b[6] = f2bf(v1[2]); b[7] = f2bf(v1[3]);
            sq += v0[0]*v0[0] + v0[1]*v0[1] + v0[2]*v0[2] + v0[3]*v0[3]
                + v1[0]*v1[0] + v1[1]*v1[1] + v1[2]*v1[2] + v1[3]*v1[3];
            const int g = t * 2048 + r * 4 + (s ^ ((r >> 1) & 3));
            *reinterpret_cast<u16x8*>(Cbws + (size_t)g * 8) = b;
        }
    }
#pragma unroll
    for (int m = 1; m < 64; m <<= 1) sq += __shfl_xor(sq, m, 64);
    if (l == 0) csq[r] = sq;
}

// Main: 64 rows x 512 clusters per block, 8 waves, wave tile 64x64.
// B: WAVE-PRIVATE 2-deep LDS slices (each wave DMAs only the 4 KB it reads),
// gated by per-wave counted vmcnt -> the per-step barrier carries NO VMEM
// wait (lgkmcnt(0) for the shared A tile only).  A: reg->LDS dbuf.
__global__ __launch_bounds__(512, 4) void dec_main_kernel(
    const float* __restrict__ X,
    const unsigned short* __restrict__ Cbws,
    const float* __restrict__ csq,
    const float* __restrict__ alpha_ptr,
    float* __restrict__ out)
{
    __shared__ unsigned short Al[2][BM * BK];        // 2 * 4 KB
    __shared__ unsigned short Bl[8 * 2 * 2048];      // 8 waves x 2 bufs x 4 KB = 64 KB
    __shared__ float part[8][BM];                    // 2 KB
    __shared__ float xsql[BM];
    __shared__ float invl[BM];

    const int tid  = threadIdx.x;      // 0..511
    const int lane = tid & 63;
    const int wn   = tid >> 6;         // 0..7
    const int m0   = blockIdx.x * BM;

    // A staging: 8 threads per row, float4 each (verified swizzle)
    const int arow  = tid >> 3;
    const int acol8 = tid & 7;
    const float* aptr = X + (size_t)(m0 + arow) * D_DIM + acol8 * 4;
    const int awbyte = arow * 64
                     + ((((acol8 >> 1) ^ ((arow >> 1) & 3))) << 4)
                     + (acol8 & 1) * 8;

    // fragment read offsets
    const int fr = lane & 15;
    const int fg = lane >> 4;
    int aoff[4], boffb[4];
#pragma unroll
    for (int mf = 0; mf < 4; ++mf) {
        const int r = mf * 16 + fr;
        aoff[mf] = r * 64 + ((fg ^ ((r >> 1) & 3)) << 4);
    }
    const int bslice = wn * 8192;      // byte offset of wave's 8 KB B region
#pragma unroll
    for (int nf = 0; nf < 4; ++nf) {
        const int lr = nf * 16 + fr;   // local row 0..63 ((global>>1)&3 == (lr>>1)&3)
        boffb[nf] = bslice + lr * 64 + ((fg ^ ((lr >> 1) & 3)) << 4);
    }

    // B DMA: wave-private slice, 4 x 1KB per step, linear copy of the image
    const unsigned short* bsrc = Cbws + (size_t)(wn * 256) * 8 + (size_t)lane * 8;
    char* bdst = (char*)&Bl[0] + bslice + lane * 16;

#define B_DMA(tt, buf_)                                                        \
    {                                                                          \
        const unsigned short* bs_ = bsrc + (size_t)(tt) * 16384;               \
        char* bd_ = bdst + (buf_) * 4096;                                      \
        gload_lds16(bs_,          bd_);                                        \
        gload_lds16(bs_ + 512,    bd_ + 1024);                                 \
        gload_lds16(bs_ + 1024,   bd_ + 2048);                                 \
        gload_lds16(bs_ + 1536,   bd_ + 3072);                                 \
    }

    f32x4 acc[4][4] = {};
    float sqp = 0.f;

    // ---- prologue ----
    f32x4 areg = *reinterpret_cast<const f32x4*>(aptr);         // A tile 0
    B_DMA(0, 0);
    {   // stage A(0)
        u16x4 ab;
        ab[0] = f2bf(areg[0]); ab[1] = f2bf(areg[1]);
        ab[2] = f2bf(areg[2]); ab[3] = f2bf(areg[3]);
        sqp += areg[0]*areg[0] + areg[1]*areg[1] + areg[2]*areg[2] + areg[3]*areg[3];
        *reinterpret_cast<u16x4*>((char*)&Al[0][0] + awbyte) = ab;
    }
    areg = *reinterpret_cast<const f32x4*>(aptr + BK);          // A tile 1
    asm volatile("s_waitcnt lgkmcnt(0)" ::: "memory");          // A(0) visible
    __builtin_amdgcn_sched_barrier(0);
    __builtin_amdgcn_s_barrier();

    for (int t = 0; t < NSTEP; ++t) {
        const int buf = t & 1;
        // 1. issue wave-private B-DMA(t+1)
        if (t + 1 < NSTEP) B_DMA(t + 1, buf ^ 1);
        __builtin_amdgcn_sched_barrier(0);
        // 2. compute(t): per-wave counted wait -> B(t) landed, B(t+1) in flight
        if (t + 1 < NSTEP)
            asm volatile("s_waitcnt vmcnt(4)" ::: "memory");
        else
            asm volatile("s_waitcnt vmcnt(0)" ::: "memory");
        {
            s16x8 afr[4];
#pragma unroll
            for (int mf = 0; mf < 4; ++mf)
                afr[mf] = *reinterpret_cast<const s16x8*>((const char*)&Al[buf][0] + aoff[mf]);
            __builtin_amdgcn_s_setprio(1);
#pragma unroll
            for (int nf = 0; nf < 4; ++nf) {
                s16x8 bfr = *reinterpret_cast<const s16x8*>(
                    (const char*)&Bl[0] + buf * 4096 + boffb[nf]);
#pragma unroll
                for (int mf = 0; mf < 4; ++mf)
                    acc[mf][nf] = __builtin_amdgcn_mfma_f32_16x16x32_bf16(
                        afr[mf], bfr, acc[mf][nf], 0, 0, 0);
            }
            __builtin_amdgcn_s_setprio(0);
        }
        // 3. stage A(t+1), prefetch areg(t+2); barrier waits on LDS only
        if (t + 1 < NSTEP) {
            u16x4 ab;
            ab[0] = f2bf(areg[0]); ab[1] = f2bf(areg[1]);
            ab[2] = f2bf(areg[2]); ab[3] = f2bf(areg[3]);
            sqp += areg[0]*areg[0] + areg[1]*areg[1] + areg[2]*areg[2] + areg[3]*areg[3];
            *reinterpret_cast<u16x4*>((char*)&Al[buf ^ 1][0] + awbyte) = ab;
            if (t + 2 < NSTEP)
                areg = *reinterpret_cast<const f32x4*>(aptr + (t + 2) * BK);
            asm volatile("s_waitcnt lgkmcnt(0)" ::: "memory");  // A publish only
            __builtin_amdgcn_sched_barrier(0);
            __builtin_amdgcn_s_barrier();
        }
    }
#undef B_DMA

    // ---- ||x||^2 per row ----
    sqp += __shfl_xor(sqp, 1, 64);
    sqp += __shfl_xor(sqp, 2, 64);
    sqp += __shfl_xor(sqp, 4, 64);
    if ((tid & 7) == 0) xsql[arow] = sqp;
    __syncthreads();

    const float alpha     = alpha_ptr[0];
    const float inv_alpha = 1.0f / alpha;
    const float power     = 0.5f * (alpha + 1.0f);
    const bool  p1        = (power == 1.0f);

    float csqr[4];
#pragma unroll
    for (int nf = 0; nf < 4; ++nf)
        csqr[nf] = csq[wn * 64 + nf * 16 + fr];

    if (p1) {
#pragma unroll
        for (int mf = 0; mf < 4; ++mf) {
#pragma unroll
            for (int j = 0; j < 4; ++j) {
                const int rloc = mf * 16 + fg * 4 + j;
                const float xs = xsql[rloc];
                float rp = 0.f;
#pragma unroll
                for (int nf = 0; nf < 4; ++nf) {
                    float d2 = xs + csqr[nf] - 2.0f * acc[mf][nf][j];
                    d2 = fmaxf(d2, 0.0f);
                    const float nm = 1.0f / (1.0f + d2 * inv_alpha);
                    acc[mf][nf][j] = nm;
                    rp += nm;
                }
#pragma unroll
                for (int m = 1; m < 16; m <<= 1) rp += __shfl_xor(rp, m, 64);
                if (fr == 0) part[wn][rloc] = rp;
            }
        }
    } else {
#pragma unroll
        for (int mf = 0; mf < 4; ++mf) {
#pragma unroll
            for (int j = 0; j < 4; ++j) {
                const int rloc = mf * 16 + fg * 4 + j;
                const float xs = xsql[rloc];
                float rp = 0.f;
#pragma unroll
                for (int nf = 0; nf < 4; ++nf) {
                    float d2 = xs + csqr[nf] - 2.0f * acc[mf][nf][j];
                    d2 = fmaxf(d2, 0.0f);
                    const float base = 1.0f + d2 * inv_alpha;
                    const float nm = exp2f(-power * log2f(base));
                    acc[mf][nf][j] = nm;
                    rp += nm;
                }
#pragma unroll
                for (int m = 1; m < 16; m <<= 1) rp += __shfl_xor(rp, m, 64);
                if (fr == 0) part[wn][rloc] = rp;
            }
        }
    }
    __syncthreads();
    if (tid < BM) {
        float s = 0.f;
#pragma unroll
        for (int w = 0; w < 8; ++w) s += part[w][tid];
        invl[tid] = 1.0f / s;
    }
    __syncthreads();

#pragma unroll
    for (int mf = 0; mf < 4; ++mf) {
#pragma unroll
        for (int j = 0; j < 4; ++j) {
            const int rloc = mf * 16 + fg * 4 + j;
            const float iv = invl[rloc];
            float* orow = out + (size_t)(m0 + rloc) * K_CL + wn * 64 + fr;
#pragma unroll
            for (int nf = 0; nf < 4; ++nf)
                orow[nf * 16] = acc[mf][nf][j] * iv;
        }
    }
}

extern "C" void kernel_launch(void* const* d_in, const int* in_sizes, int n_in,
                              void* d_out, int out_size, void* d_ws, size_t ws_size,
                              hipStream_t stream) {
    const float* X     = (const float*)d_in[0];
    const float* C     = (const float*)d_in[1];
    const float* alpha = (const float*)d_in[2];
    float* out = (float*)d_out;
    const int N = in_sizes[0] / D_DIM;   // 65536

    unsigned short* Cbws = (unsigned short*)d_ws;
    float* csq = (float*)((char*)d_ws + (size_t)K_CL * D_DIM * sizeof(unsigned short));

    prep_centers_kernel<<<K_CL, 64, 0, stream>>>(C, Cbws, csq);
    dec_main_kernel<<<N / BM, 512, 0, stream>>>(X, Cbws, csq, alpha, out);
}